// Round 2
// baseline (1557.858 us; speedup 1.0000x reference)
//
#include <hip/hip_runtime.h>
#include <stdint.h>

#define N_NODES 100000
#define D 128

// Phase 2: scatter-add of h[src] rows into msg[dst], plus degree count.
// 2 edges per 256-thread block; 128 threads per edge (one feature each).
__global__ __launch_bounds__(256) void scatter_k(
    const float* __restrict__ h,
    const int* __restrict__ src, const int* __restrict__ dst,
    float* __restrict__ msg, float* __restrict__ deg, int n_edges)
{
    int e = blockIdx.x * 2 + (threadIdx.x >> 7);
    if (e >= n_edges) return;
    int f = threadIdx.x & 127;
    int s = src[e];
    int d = dst[e];
    float v = h[(size_t)s * D + f];
    unsafeAtomicAdd(&msg[(size_t)d * D + f], v);
    if (f == 0) unsafeAtomicAdd(&deg[d], 1.0f);
}

// Phase 3: h_N = msg/deg (0 if deg==0); out = [h, h_N] @ W + b.
// One wave per node. Lane l owns output cols 2l, 2l+1.
// n is wave-uniform so h/msg row reads scalarize (s_load broadcast).
__global__ __launch_bounds__(256) void fin_k(
    const float* __restrict__ h,
    const float* __restrict__ msg, const float* __restrict__ deg,
    const float* __restrict__ W, const float* __restrict__ b,
    float* __restrict__ out)
{
    int wv = threadIdx.x >> 6;
    int lane = threadIdx.x & 63;
    int n = blockIdx.x * 4 + wv;
    if (n >= N_NODES) return;
    n = __builtin_amdgcn_readfirstlane(n);

    float dg = deg[n];
    float invd = dg > 0.0f ? 1.0f / dg : 0.0f;

    const float* hrow = h + (size_t)n * D;
    const float* mrow = msg + (size_t)n * D;
    int j0 = lane * 2;

    float acc0 = 0.f, acc1 = 0.f;

    #pragma unroll 8
    for (int k = 0; k < D; ++k) {
        float a = hrow[k];
        float2 w = *(const float2*)(W + (size_t)k * D + j0);
        acc0 += a * w.x;
        acc1 += a * w.y;
    }
    #pragma unroll 8
    for (int k = 0; k < D; ++k) {
        float a = mrow[k] * invd;
        float2 w = *(const float2*)(W + (size_t)(k + D) * D + j0);
        acc0 += a * w.x;
        acc1 += a * w.y;
    }

    acc0 += b[j0];
    acc1 += b[j0 + 1];

    float2 o = make_float2(acc0, acc1);
    *(float2*)(out + (size_t)n * D + j0) = o;
}

extern "C" void kernel_launch(void* const* d_in, const int* in_sizes, int n_in,
                              void* d_out, int out_size, void* d_ws, size_t ws_size,
                              hipStream_t stream) {
    const float* h  = (const float*)d_in[0];
    const int* src  = (const int*)d_in[1];
    const int* dst  = (const int*)d_in[2];
    const float* W  = (const float*)d_in[3];
    const float* b  = (const float*)d_in[4];
    float* out      = (float*)d_out;
    int n_edges = in_sizes[1];

    float* msg = (float*)d_ws;                       // [N_NODES * D] fp32
    float* deg = msg + (size_t)N_NODES * D;          // [N_NODES] fp32

    hipMemsetAsync(d_ws, 0, ((size_t)N_NODES * D + N_NODES) * sizeof(float), stream);

    int sblocks = (n_edges + 1) / 2;
    hipLaunchKernelGGL(scatter_k, dim3(sblocks), dim3(256), 0, stream,
                       h, src, dst, msg, deg, n_edges);

    hipLaunchKernelGGL(fin_k, dim3((N_NODES + 3) / 4), dim3(256), 0, stream,
                       h, msg, deg, W, b, out);
}

// Round 3
// 530.726 us; speedup vs baseline: 2.9353x; 2.9353x over previous
//
#include <hip/hip_runtime.h>
#include <stdint.h>

#define N_NODES 100000
#define D 128
#define SCAN_CHUNK 1024
#define NBLK ((N_NODES + SCAN_CHUNK - 1) / SCAN_CHUNK)  // 98

// ---- CSR build ------------------------------------------------------------

__global__ __launch_bounds__(256) void hist_k(
    const int* __restrict__ dst, int* __restrict__ counts, int n_edges)
{
    int e = blockIdx.x * 256 + threadIdx.x;
    if (e < n_edges) atomicAdd(&counts[dst[e]], 1);
}

// per-chunk (1024) reduce -> bsum[98]
__global__ __launch_bounds__(256) void scan1_k(
    const int* __restrict__ counts, int* __restrict__ bsum)
{
    __shared__ int s[256];
    int base = blockIdx.x * SCAN_CHUNK;
    int t = threadIdx.x;
    int sum = 0;
    #pragma unroll
    for (int i = 0; i < 4; ++i) {
        int idx = base + t * 4 + i;
        if (idx < N_NODES) sum += counts[idx];
    }
    s[t] = sum;
    __syncthreads();
    for (int off = 128; off > 0; off >>= 1) {
        if (t < off) s[t] += s[t + off];
        __syncthreads();
    }
    if (t == 0) bsum[blockIdx.x] = s[0];
}

// exclusive scan of bsum (98 values), single block
__global__ __launch_bounds__(128) void scan2_k(int* __restrict__ bsum)
{
    __shared__ int s[NBLK];
    int t = threadIdx.x;
    if (t < NBLK) s[t] = bsum[t];
    __syncthreads();
    if (t == 0) {
        int run = 0;
        for (int i = 0; i < NBLK; ++i) { int v = s[i]; s[i] = run; run += v; }
    }
    __syncthreads();
    if (t < NBLK) bsum[t] = s[t];
}

// per-chunk exclusive scan + block carry -> offsets
__global__ __launch_bounds__(256) void scan3_k(
    const int* __restrict__ counts, const int* __restrict__ bsum,
    int* __restrict__ offsets)
{
    __shared__ int s[256];
    int base = blockIdx.x * SCAN_CHUNK;
    int t = threadIdx.x;
    int v[4]; int sum = 0;
    #pragma unroll
    for (int i = 0; i < 4; ++i) {
        int idx = base + t * 4 + i;
        v[i] = (idx < N_NODES) ? counts[idx] : 0;
        sum += v[i];
    }
    s[t] = sum;
    __syncthreads();
    for (int off = 1; off < 256; off <<= 1) {
        int val = (t >= off) ? s[t - off] : 0;
        __syncthreads();
        s[t] += val;
        __syncthreads();
    }
    int run = bsum[blockIdx.x] + s[t] - sum;   // exclusive prefix for this thread
    #pragma unroll
    for (int i = 0; i < 4; ++i) {
        int idx = base + t * 4 + i;
        if (idx < N_NODES) offsets[idx] = run;
        run += v[i];
    }
}

// fill CSR; mutates offsets[n] -> end offset (start = end - counts[n])
__global__ __launch_bounds__(256) void fill_k(
    const int* __restrict__ src, const int* __restrict__ dst,
    int* __restrict__ offsets, int* __restrict__ csr, int n_edges)
{
    int e = blockIdx.x * 256 + threadIdx.x;
    if (e < n_edges) {
        int d = dst[e];
        int pos = atomicAdd(&offsets[d], 1);
        csr[pos] = src[e];
    }
}

// ---- gather-mean: hN[n] = mean(h[csr[n]]) ---------------------------------
// one wave per node; lane covers features [2*lane, 2*lane+1]
__global__ __launch_bounds__(256) void agg_k(
    const float* __restrict__ h, const int* __restrict__ csr,
    const int* __restrict__ offsets, const int* __restrict__ counts,
    float* __restrict__ hN)
{
    int wv = threadIdx.x >> 6, lane = threadIdx.x & 63;
    int n = blockIdx.x * 4 + wv;
    if (n >= N_NODES) return;
    n = __builtin_amdgcn_readfirstlane(n);

    int dg  = counts[n];
    int off = offsets[n] - dg;     // offsets[n] is the END after fill_k
    int f = lane * 2;

    float ax = 0.f, ay = 0.f;
    int e = 0;
    for (; e + 4 <= dg; e += 4) {
        int s0 = csr[off + e], s1 = csr[off + e + 1];
        int s2 = csr[off + e + 2], s3 = csr[off + e + 3];
        float2 v0 = *(const float2*)(h + (size_t)s0 * D + f);
        float2 v1 = *(const float2*)(h + (size_t)s1 * D + f);
        float2 v2 = *(const float2*)(h + (size_t)s2 * D + f);
        float2 v3 = *(const float2*)(h + (size_t)s3 * D + f);
        ax += (v0.x + v1.x) + (v2.x + v3.x);
        ay += (v0.y + v1.y) + (v2.y + v3.y);
    }
    for (; e < dg; ++e) {
        int s0 = csr[off + e];
        float2 v = *(const float2*)(h + (size_t)s0 * D + f);
        ax += v.x; ay += v.y;
    }
    float invd = dg > 0 ? 1.0f / (float)dg : 0.f;
    float2 o = make_float2(ax * invd, ay * invd);
    *(float2*)(hN + (size_t)n * D + f) = o;
}

// ---- tiled GEMM: out[64-node tile][128] = [h|hN] @ W + b ------------------
// 256 threads: tx = tid&31 -> cols tx*4..+3 ; ty = tid>>5 -> nodes ty*8..+7
#define KT 16
__global__ __launch_bounds__(256) void gemm_k(
    const float* __restrict__ h, const float* __restrict__ hN,
    const float* __restrict__ W, const float* __restrict__ bias,
    float* __restrict__ out)
{
    __shared__ float As[64][20];     // 64 nodes x KT (pad 20 for b128 stores)
    __shared__ float Ws[KT][132];    // KT x 128 cols (pad 132)

    int tid = threadIdx.x;
    int n0 = blockIdx.x * 64;
    int tx = tid & 31, ty = tid >> 5;

    float4 acc[8];
    #pragma unroll
    for (int r = 0; r < 8; ++r) acc[r] = make_float4(0.f, 0.f, 0.f, 0.f);

    // A-tile load mapping: row = tid>>2 (0..63), q = tid&3 -> k offset q*4
    int arow = tid >> 2, aq = (tid & 3) * 4;
    int anode = n0 + arow; if (anode >= N_NODES) anode = N_NODES - 1;
    // W-tile load mapping: 2048 elems, 8/thread: wr = tid>>4, wc = (tid&15)*8
    int wr = tid >> 4, wc = (tid & 15) * 8;

    for (int k0 = 0; k0 < 2 * D; k0 += KT) {
        const float* asrc = (k0 < D) ? (h + (size_t)anode * D + k0 + aq)
                                     : (hN + (size_t)anode * D + (k0 - D) + aq);
        float4 av = *(const float4*)asrc;
        float4 wv0 = *(const float4*)(W + (size_t)(k0 + wr) * D + wc);
        float4 wv1 = *(const float4*)(W + (size_t)(k0 + wr) * D + wc + 4);
        __syncthreads();
        *(float4*)&As[arow][aq] = av;
        *(float4*)&Ws[wr][wc] = wv0;
        *(float4*)&Ws[wr][wc + 4] = wv1;
        __syncthreads();

        #pragma unroll
        for (int kk = 0; kk < KT; kk += 2) {
            float4 w0 = *(const float4*)&Ws[kk][tx * 4];
            float4 w1 = *(const float4*)&Ws[kk + 1][tx * 4];
            #pragma unroll
            for (int r = 0; r < 8; ++r) {
                float2 a = *(const float2*)&As[ty * 8 + r][kk];
                acc[r].x += a.x * w0.x + a.y * w1.x;
                acc[r].y += a.x * w0.y + a.y * w1.y;
                acc[r].z += a.x * w0.z + a.y * w1.z;
                acc[r].w += a.x * w0.w + a.y * w1.w;
            }
        }
    }

    float4 bv = *(const float4*)(bias + tx * 4);
    #pragma unroll
    for (int r = 0; r < 8; ++r) {
        int node = n0 + ty * 8 + r;
        if (node < N_NODES) {
            float4 o = make_float4(acc[r].x + bv.x, acc[r].y + bv.y,
                                   acc[r].z + bv.z, acc[r].w + bv.w);
            *(float4*)(out + (size_t)node * D + tx * 4) = o;
        }
    }
}

// ---- launch ---------------------------------------------------------------

extern "C" void kernel_launch(void* const* d_in, const int* in_sizes, int n_in,
                              void* d_out, int out_size, void* d_ws, size_t ws_size,
                              hipStream_t stream) {
    const float* h  = (const float*)d_in[0];
    const int* src  = (const int*)d_in[1];
    const int* dst  = (const int*)d_in[2];
    const float* W  = (const float*)d_in[3];
    const float* b  = (const float*)d_in[4];
    float* out      = (float*)d_out;
    int n_edges = in_sizes[1];

    // workspace layout
    char* ws = (char*)d_ws;
    float* hN     = (float*)ws;                                   // 51.2 MB
    int*   counts = (int*)(ws + (size_t)N_NODES * D * 4);         // 400 KB
    int*   offs   = counts + N_NODES;                             // 400 KB
    int*   bsum   = offs + N_NODES;                               // 512 B
    int*   csr    = bsum + 128;                                   // 6.4 MB

    hipMemsetAsync(counts, 0, N_NODES * sizeof(int), stream);

    int eblocks = (n_edges + 255) / 256;
    hipLaunchKernelGGL(hist_k,  dim3(eblocks), dim3(256), 0, stream, dst, counts, n_edges);
    hipLaunchKernelGGL(scan1_k, dim3(NBLK),    dim3(256), 0, stream, counts, bsum);
    hipLaunchKernelGGL(scan2_k, dim3(1),       dim3(128), 0, stream, bsum);
    hipLaunchKernelGGL(scan3_k, dim3(NBLK),    dim3(256), 0, stream, counts, bsum, offs);
    hipLaunchKernelGGL(fill_k,  dim3(eblocks), dim3(256), 0, stream, src, dst, offs, csr, n_edges);
    hipLaunchKernelGGL(agg_k,   dim3((N_NODES + 3) / 4), dim3(256), 0, stream,
                       h, csr, offs, counts, hN);
    hipLaunchKernelGGL(gemm_k,  dim3((N_NODES + 63) / 64), dim3(256), 0, stream,
                       h, hN, W, b, out);
}

// Round 4
// 410.163 us; speedup vs baseline: 3.7981x; 1.2939x over previous
//
#include <hip/hip_runtime.h>
#include <stdint.h>

#define N_NODES 100000
#define D 128
#define SCAN_CHUNK 1024
#define NBLK ((N_NODES + SCAN_CHUNK - 1) / SCAN_CHUNK)  // 98

typedef short bf16x8 __attribute__((ext_vector_type(8)));
typedef float f32x4 __attribute__((ext_vector_type(4)));

__device__ __forceinline__ float bf2f(unsigned short u) {
    return __uint_as_float(((unsigned int)u) << 16);
}
__device__ __forceinline__ unsigned short f2bf(float f) {
    unsigned int x = __float_as_uint(f);
    unsigned int r = x + 0x7fffu + ((x >> 16) & 1u);
    return (unsigned short)(r >> 16);
}

// ---- CSR build ------------------------------------------------------------

__global__ __launch_bounds__(256) void hist_k(
    const int* __restrict__ dst, int* __restrict__ counts, int n_edges)
{
    int e = blockIdx.x * 256 + threadIdx.x;
    if (e < n_edges) atomicAdd(&counts[dst[e]], 1);
}

__global__ __launch_bounds__(256) void scan1_k(
    const int* __restrict__ counts, int* __restrict__ bsum)
{
    __shared__ int s[256];
    int base = blockIdx.x * SCAN_CHUNK;
    int t = threadIdx.x;
    int sum = 0;
    #pragma unroll
    for (int i = 0; i < 4; ++i) {
        int idx = base + t * 4 + i;
        if (idx < N_NODES) sum += counts[idx];
    }
    s[t] = sum;
    __syncthreads();
    for (int off = 128; off > 0; off >>= 1) {
        if (t < off) s[t] += s[t + off];
        __syncthreads();
    }
    if (t == 0) bsum[blockIdx.x] = s[0];
}

__global__ __launch_bounds__(128) void scan2_k(int* __restrict__ bsum)
{
    __shared__ int s[NBLK];
    int t = threadIdx.x;
    if (t < NBLK) s[t] = bsum[t];
    __syncthreads();
    if (t == 0) {
        int run = 0;
        for (int i = 0; i < NBLK; ++i) { int v = s[i]; s[i] = run; run += v; }
    }
    __syncthreads();
    if (t < NBLK) bsum[t] = s[t];
}

__global__ __launch_bounds__(256) void scan3_k(
    const int* __restrict__ counts, const int* __restrict__ bsum,
    int* __restrict__ offsets)
{
    __shared__ int s[256];
    int base = blockIdx.x * SCAN_CHUNK;
    int t = threadIdx.x;
    int v[4]; int sum = 0;
    #pragma unroll
    for (int i = 0; i < 4; ++i) {
        int idx = base + t * 4 + i;
        v[i] = (idx < N_NODES) ? counts[idx] : 0;
        sum += v[i];
    }
    s[t] = sum;
    __syncthreads();
    for (int off = 1; off < 256; off <<= 1) {
        int val = (t >= off) ? s[t - off] : 0;
        __syncthreads();
        s[t] += val;
        __syncthreads();
    }
    int run = bsum[blockIdx.x] + s[t] - sum;
    #pragma unroll
    for (int i = 0; i < 4; ++i) {
        int idx = base + t * 4 + i;
        if (idx < N_NODES) offsets[idx] = run;
        run += v[i];
    }
}

// fill CSR; mutates offsets[n] -> end offset (start = end - counts[n])
__global__ __launch_bounds__(256) void fill_k(
    const int* __restrict__ src, const int* __restrict__ dst,
    int* __restrict__ offsets, int* __restrict__ csr, int n_edges)
{
    int e = blockIdx.x * 256 + threadIdx.x;
    if (e < n_edges) {
        int d = dst[e];
        int pos = atomicAdd(&offsets[d], 1);
        csr[pos] = src[e];
    }
}

// ---- conversions ----------------------------------------------------------

// h fp32 -> bf16, 4 elems/thread
__global__ __launch_bounds__(256) void conv_h_k(
    const float* __restrict__ h, unsigned short* __restrict__ h_bf)
{
    size_t base = ((size_t)blockIdx.x * 256 + threadIdx.x) * 4;
    if (base >= (size_t)N_NODES * D) return;
    float4 v = *(const float4*)(h + base);
    ushort4 o;
    o.x = f2bf(v.x); o.y = f2bf(v.y); o.z = f2bf(v.z); o.w = f2bf(v.w);
    *(ushort4*)(h_bf + base) = o;
}

// Pack W [256][128] fp32 into bf16 B-fragment order:
// frag f = kt*8+ct (kt: k-tile of 32, ct: col-tile of 16); within frag,
// lane l holds W[kt*32 + (l>>4)*8 + j][ct*16 + (l&15)], j=0..7, stored
// contiguously at Wf[f*512 + l*8 + j].
__global__ __launch_bounds__(256) void wprep_k(
    const float* __restrict__ W, unsigned short* __restrict__ Wf)
{
    int gid = blockIdx.x * 256 + threadIdx.x;   // 4096 threads: (frag, lane)
    if (gid >= 64 * 64) return;
    int f = gid >> 6, l = gid & 63;
    int kt = f >> 3, ct = f & 7;
    int n = ct * 16 + (l & 15);
    int kb = kt * 32 + (l >> 4) * 8;
    #pragma unroll
    for (int j = 0; j < 8; ++j)
        Wf[(size_t)f * 512 + l * 8 + j] = f2bf(W[(size_t)(kb + j) * D + n]);
}

// ---- gather-mean: hN_bf[n] = mean(h_bf[csr[n]]) ---------------------------
__global__ __launch_bounds__(256) void agg_k(
    const unsigned short* __restrict__ h_bf, const int* __restrict__ csr,
    const int* __restrict__ offsets, const int* __restrict__ counts,
    unsigned short* __restrict__ hN_bf)
{
    int wv = threadIdx.x >> 6, lane = threadIdx.x & 63;
    int n = blockIdx.x * 4 + wv;
    if (n >= N_NODES) return;
    n = __builtin_amdgcn_readfirstlane(n);

    int dg  = counts[n];
    int off = offsets[n] - dg;     // offsets[n] is END after fill_k
    int f = lane * 2;

    float ax = 0.f, ay = 0.f;
    int e = 0;
    for (; e + 4 <= dg; e += 4) {
        int s0 = csr[off + e], s1 = csr[off + e + 1];
        int s2 = csr[off + e + 2], s3 = csr[off + e + 3];
        unsigned int u0 = *(const unsigned int*)(h_bf + (size_t)s0 * D + f);
        unsigned int u1 = *(const unsigned int*)(h_bf + (size_t)s1 * D + f);
        unsigned int u2 = *(const unsigned int*)(h_bf + (size_t)s2 * D + f);
        unsigned int u3 = *(const unsigned int*)(h_bf + (size_t)s3 * D + f);
        ax += (bf2f(u0 & 0xffff) + bf2f(u1 & 0xffff)) + (bf2f(u2 & 0xffff) + bf2f(u3 & 0xffff));
        ay += (bf2f(u0 >> 16) + bf2f(u1 >> 16)) + (bf2f(u2 >> 16) + bf2f(u3 >> 16));
    }
    for (; e < dg; ++e) {
        int s0 = csr[off + e];
        unsigned int u = *(const unsigned int*)(h_bf + (size_t)s0 * D + f);
        ax += bf2f(u & 0xffff); ay += bf2f(u >> 16);
    }
    float invd = dg > 0 ? 1.0f / (float)dg : 0.f;
    unsigned int o = ((unsigned int)f2bf(ay * invd) << 16) | f2bf(ax * invd);
    *(unsigned int*)(hN_bf + (size_t)n * D + f) = o;
}

// ---- MFMA GEMM: out[128-node tile][128] = [h_bf|hN_bf] @ W + b ------------
// 4 waves/block; wave w owns rows n0+w*32..+31 (2 row-groups of 16).
// acc[2][8] 16x16 frags. B-frags stream from Wf (L2-resident, 16B/lane).
__global__ __launch_bounds__(256) void gemm_k(
    const unsigned short* __restrict__ h_bf, const unsigned short* __restrict__ hN_bf,
    const unsigned short* __restrict__ Wf, const float* __restrict__ bias,
    float* __restrict__ out)
{
    int tid = threadIdx.x;
    int w = tid >> 6, l = tid & 63;
    int n0 = blockIdx.x * 128 + w * 32;
    int lrow = l & 15, lq = l >> 4;

    int r0 = n0 + lrow;      if (r0 > N_NODES - 1) r0 = N_NODES - 1;
    int r1 = n0 + 16 + lrow; if (r1 > N_NODES - 1) r1 = N_NODES - 1;

    f32x4 acc[2][8];
    #pragma unroll
    for (int rg = 0; rg < 2; ++rg)
        #pragma unroll
        for (int ct = 0; ct < 8; ++ct)
            acc[rg][ct] = (f32x4){0.f, 0.f, 0.f, 0.f};

    const unsigned short* wf_lane = Wf + l * 8;

    #pragma unroll
    for (int kt = 0; kt < 8; ++kt) {
        const unsigned short* Abase = (kt < 4) ? h_bf : hN_bf;
        int ko = (kt & 3) * 32 + lq * 8;
        bf16x8 a0 = *(const bf16x8*)(Abase + (size_t)r0 * D + ko);
        bf16x8 a1 = *(const bf16x8*)(Abase + (size_t)r1 * D + ko);
        #pragma unroll
        for (int ct = 0; ct < 8; ++ct) {
            bf16x8 b = *(const bf16x8*)(wf_lane + (size_t)(kt * 8 + ct) * 512);
            acc[0][ct] = __builtin_amdgcn_mfma_f32_16x16x32_bf16(a0, b, acc[0][ct], 0, 0, 0);
            acc[1][ct] = __builtin_amdgcn_mfma_f32_16x16x32_bf16(a1, b, acc[1][ct], 0, 0, 0);
        }
    }

    // D layout: col = l&15, row = (l>>4)*4 + reg
    int col = l & 15, q = l >> 4;
    #pragma unroll
    for (int ct = 0; ct < 8; ++ct) {
        float bv = bias[ct * 16 + col];
        #pragma unroll
        for (int rg = 0; rg < 2; ++rg) {
            #pragma unroll
            for (int r = 0; r < 4; ++r) {
                int row = n0 + rg * 16 + q * 4 + r;
                if (row < N_NODES)
                    out[(size_t)row * D + ct * 16 + col] = acc[rg][ct][r] + bv;
            }
        }
    }
}

// ---- launch ---------------------------------------------------------------

extern "C" void kernel_launch(void* const* d_in, const int* in_sizes, int n_in,
                              void* d_out, int out_size, void* d_ws, size_t ws_size,
                              hipStream_t stream) {
    const float* h  = (const float*)d_in[0];
    const int* src  = (const int*)d_in[1];
    const int* dst  = (const int*)d_in[2];
    const float* W  = (const float*)d_in[3];
    const float* b  = (const float*)d_in[4];
    float* out      = (float*)d_out;
    int n_edges = in_sizes[1];

    // workspace layout (~58.5 MB)
    char* ws = (char*)d_ws;
    unsigned short* h_bf  = (unsigned short*)ws;                       // 25.6 MB
    unsigned short* hN_bf = h_bf + (size_t)N_NODES * D;                // 25.6 MB
    int*   counts = (int*)(hN_bf + (size_t)N_NODES * D);               // 400 KB
    int*   offs   = counts + N_NODES;                                  // 400 KB
    int*   bsum   = offs + N_NODES;                                    // 512 B
    int*   csr    = bsum + 128;                                        // 6.4 MB
    unsigned short* Wf = (unsigned short*)(csr + 1600000);             // 64 KB

    hipMemsetAsync(counts, 0, N_NODES * sizeof(int), stream);

    int eblocks = (n_edges + 255) / 256;
    hipLaunchKernelGGL(hist_k,  dim3(eblocks), dim3(256), 0, stream, dst, counts, n_edges);
    hipLaunchKernelGGL(scan1_k, dim3(NBLK),    dim3(256), 0, stream, counts, bsum);
    hipLaunchKernelGGL(scan2_k, dim3(1),       dim3(128), 0, stream, bsum);
    hipLaunchKernelGGL(scan3_k, dim3(NBLK),    dim3(256), 0, stream, counts, bsum, offs);
    hipLaunchKernelGGL(fill_k,  dim3(eblocks), dim3(256), 0, stream, src, dst, offs, csr, n_edges);

    int cblocks = (int)(((size_t)N_NODES * D / 4 + 255) / 256);
    hipLaunchKernelGGL(conv_h_k, dim3(cblocks), dim3(256), 0, stream, h, h_bf);
    hipLaunchKernelGGL(wprep_k,  dim3(16),      dim3(256), 0, stream, W, Wf);

    hipLaunchKernelGGL(agg_k,  dim3((N_NODES + 3) / 4), dim3(256), 0, stream,
                       h_bf, csr, offs, counts, hN_bf);
    hipLaunchKernelGGL(gemm_k, dim3((N_NODES + 127) / 128), dim3(256), 0, stream,
                       h_bf, hN_bf, Wf, b, out);
}